// Round 4
// baseline (379.654 us; speedup 1.0000x reference)
//
#include <hip/hip_runtime.h>
#include <math.h>

// Problem constants
#define NTOK 16384     // B*N_PATCH
#define NPRO 1005      // C*K
#define DIMD 768
#define CKD  1005
#define CC   201
#define KKp  5
#define BGC  200
#define KEXP 2304      // expanded K = 3*768 (hh, lh, hl)
#define KA   1536      // A2 row length ([Ah|Al])
#define NPAD 1024      // padded N

// d_out section offsets (floats)
#define OUT_LOGITS   0
#define OUT_IMG      16465920
#define OUT_CLS      (OUT_IMG + 64320)
#define OUT_PART     (OUT_CLS + 12800)
#define OUT_NEWPROTO (OUT_PART + 16384)
#define OUT_PSEUDO   (OUT_NEWPROTO + 771840)

// ws byte offsets
#define WOFF_PACC    0ULL                  // 201*5*768*4 = 3,087,360
#define WOFF_A2      3087360ULL            // 16384*1536*2 = 50,331,648
#define WOFF_B2      53419008ULL           // 1024*2304*2  =  4,718,592
#define WOFF_INVTOK  58137600ULL           // 65,536
#define WOFF_PL      58203136ULL           // 65,536
#define WOFF_Q       58268672ULL           // 327,680
#define WOFF_OFFSETS 58596352ULL           // 1,024
#define WOFF_ORDER   58597376ULL           // 65,536

typedef __attribute__((ext_vector_type(8))) short short8;
typedef __attribute__((ext_vector_type(4))) float f32x4;
typedef __attribute__((ext_vector_type(4))) unsigned short usv4;

__device__ __forceinline__ unsigned short f2bf(float x) {
  unsigned int b = __float_as_uint(x);
  unsigned int r = (b + 0x7FFFu + ((b >> 16) & 1u)) >> 16;
  return (unsigned short)r;
}
__device__ __forceinline__ float bf2f(unsigned short u) {
  return __uint_as_float(((unsigned int)u) << 16);
}

__device__ __forceinline__ void async_copy16(const void* g, void* lds) {
  __builtin_amdgcn_global_load_lds(
      (const __attribute__((address_space(1))) unsigned int*)g,
      (__attribute__((address_space(3))) unsigned int*)lds, 16, 0, 0);
}

// ---------------- fused convert: tokens + prototypes -> A2 / B2 --------------
__global__ __launch_bounds__(256) void conv_kernel(const float* __restrict__ tok,
                                                   const float* __restrict__ pro,
                                                   unsigned short* __restrict__ A2,
                                                   unsigned short* __restrict__ B2,
                                                   float* __restrict__ inv_tok) {
  int wid = (blockIdx.x * 256 + threadIdx.x) >> 6;
  int lane = threadIdx.x & 63;
  if (wid >= NTOK + NPAD) return;

  if (wid < NTOK) {
    const float4* s4 = (const float4*)(tok + (size_t)wid * DIMD);
    float4 v[3];
    float s = 0.0f;
#pragma unroll
    for (int p = 0; p < 3; ++p) {
      v[p] = s4[p * 64 + lane];
      s += v[p].x * v[p].x + v[p].y * v[p].y + v[p].z * v[p].z + v[p].w * v[p].w;
    }
#pragma unroll
    for (int off = 32; off; off >>= 1) s += __shfl_xor(s, off, 64);
    float inv = 1.0f / (sqrtf(s) + 1e-12f);
    if (lane == 0) inv_tok[wid] = inv;
    unsigned short* rowp = A2 + (size_t)wid * KA;
#pragma unroll
    for (int p = 0; p < 3; ++p) {
      float x0 = v[p].x * inv, x1 = v[p].y * inv, x2 = v[p].z * inv, x3 = v[p].w * inv;
      usv4 hi, lo;
      hi.x = f2bf(x0); hi.y = f2bf(x1); hi.z = f2bf(x2); hi.w = f2bf(x3);
      lo.x = f2bf(x0 - bf2f(hi.x)); lo.y = f2bf(x1 - bf2f(hi.y));
      lo.z = f2bf(x2 - bf2f(hi.z)); lo.w = f2bf(x3 - bf2f(hi.w));
      int c = p * 256 + lane * 4;
      *(usv4*)(rowp + c) = hi;
      *(usv4*)(rowp + 768 + c) = lo;
    }
  } else {
    int pw = wid - NTOK;
    unsigned short* rowp = B2 + (size_t)pw * KEXP;
    if (pw >= NPRO) {
      usv4 z = {0, 0, 0, 0};
#pragma unroll
      for (int p = 0; p < 3; ++p) {
        int c = p * 256 + lane * 4;
        *(usv4*)(rowp + c) = z; *(usv4*)(rowp + 768 + c) = z; *(usv4*)(rowp + 1536 + c) = z;
      }
      return;
    }
    const float4* s4 = (const float4*)(pro + (size_t)pw * DIMD);
    float4 v[3];
    float s = 0.0f;
#pragma unroll
    for (int p = 0; p < 3; ++p) {
      v[p] = s4[p * 64 + lane];
      s += v[p].x * v[p].x + v[p].y * v[p].y + v[p].z * v[p].z + v[p].w * v[p].w;
    }
#pragma unroll
    for (int off = 32; off; off >>= 1) s += __shfl_xor(s, off, 64);
    float inv = 1.0f / (sqrtf(s) + 1e-12f);
#pragma unroll
    for (int p = 0; p < 3; ++p) {
      float x0 = v[p].x * inv, x1 = v[p].y * inv, x2 = v[p].z * inv, x3 = v[p].w * inv;
      usv4 hi, lo;
      hi.x = f2bf(x0); hi.y = f2bf(x1); hi.z = f2bf(x2); hi.w = f2bf(x3);
      lo.x = f2bf(x0 - bf2f(hi.x)); lo.y = f2bf(x1 - bf2f(hi.y));
      lo.z = f2bf(x2 - bf2f(hi.z)); lo.w = f2bf(x3 - bf2f(hi.w));
      int c = p * 256 + lane * 4;
      *(usv4*)(rowp + c) = hi;
      *(usv4*)(rowp + 768 + c) = hi;
      *(usv4*)(rowp + 1536 + c) = lo;
    }
  }
}

// ---------------- prep: mask probe + pseudo labels + hist + scan + scatter ----
// Single block, 1024 threads, 16 rows/thread. No logits dependency.
__global__ __launch_bounds__(1024) void prep_kernel(const void* __restrict__ masks,
                                                    const int* __restrict__ labels,
                                                    int* __restrict__ pl,
                                                    float* __restrict__ out_pseudo,
                                                    int* __restrict__ offsets,
                                                    int* __restrict__ order) {
  __shared__ int hist[256];
  __shared__ int cur[256];
  __shared__ int flagS;
  int t = threadIdx.x;
  int lane = t & 63;
  if (t < 256) hist[t] = 0;
  if (t == 0) flagS = 0;
  __syncthreads();

  // dtype probe over first 4096 u32 words (16 KiB, valid in all layouts)
  const unsigned* mu = (const unsigned*)masks;
  unsigned pr = 0;
  for (int i = t; i < 4096; i += 1024) {
    unsigned v = mu[i];
    if (v == 0x3F800000u)      pr |= 1;   // float32 1.0f
    else if (v > 1u)           pr |= 2;   // byte-packed
  }
  if (pr) atomicOr(&flagS, (int)pr);
  __syncthreads();
  int f = flagS;

  // labels + histogram
  int lab[16];
#pragma unroll
  for (int r = 0; r < 16; ++r) {
    int n = r * 1024 + t;
    int m;
    if (f & 1)      m = ((const float*)masks)[n] != 0.0f;
    else if (f & 2) m = ((const unsigned char*)masks)[n] != 0;
    else            m = ((const int*)masks)[n] != 0;
    int l = m ? labels[n >> 8] : BGC;
    lab[r] = l;
    pl[n] = l;
    out_pseudo[n] = (float)l;
    atomicAdd(&hist[l], 1);
  }
  __syncthreads();

  // inclusive scan of hist[0..255] (Hillis-Steele; all threads hit barriers)
  int own = (t < 256) ? hist[t] : 0;
  for (int off = 1; off < 256; off <<= 1) {
    int u = (t >= off && t < 256) ? hist[t - off] : 0;
    __syncthreads();
    if (t < 256) hist[t] += u;
    __syncthreads();
  }
  if (t < 256) {
    int excl = hist[t] - own;
    cur[t] = excl;
    if (t <= CC) offsets[t] = (t < CC) ? excl : hist[CC - 1];
  }
  if (t == CC - 1) offsets[CC] = hist[CC - 1];
  __syncthreads();

  // scatter (order within class unstable — downstream is order-independent)
#pragma unroll
  for (int r = 0; r < 16; ++r) {
    int n = r * 1024 + t;
    int l = lab[r];
    unsigned long long mk = __ballot(l == BGC);
    if (l == BGC) {
      int rank = __popcll(mk & ((1ull << lane) - 1));
      int leader = (int)(__ffsll((long long)mk) - 1);
      int base = 0;
      if (lane == leader) base = atomicAdd(&cur[BGC], (int)__popcll(mk));
      base = __shfl(base, leader, 64);
      order[base + rank] = n;
    } else {
      order[atomicAdd(&cur[l], 1)] = n;
    }
  }
}

// ---------------- MFMA GEMM (unchanged from round 3) -------------------------
__global__ __launch_bounds__(256, 2) void gemm_kernel(const unsigned short* __restrict__ A2,
                                                      const unsigned short* __restrict__ B2,
                                                      float* __restrict__ C,
                                                      float* __restrict__ img) {
  __shared__ unsigned short As[2][4096];   // [128 rows][32 k] bf16
  __shared__ unsigned short Bs[2][4096];
  const int tid = threadIdx.x;
  const int lane = tid & 63, wave = tid >> 6;
  const int m0 = blockIdx.x * 128, n0 = blockIdx.y * 128;
  const int wr = wave >> 1, wc = wave & 1;

  f32x4 acc[4][4];
#pragma unroll
  for (int i = 0; i < 4; ++i)
#pragma unroll
    for (int j = 0; j < 4; ++j) acc[i][j] = (f32x4){0.f, 0.f, 0.f, 0.f};

  const int r4 = lane >> 2;
  const int kc = (lane & 3) * 8;

  auto STAGE = [&](int buf, int kt) {
    int kb = kt * 32;
    int acol = (kb < KA ? kb : kb - KA) + kc;
    int bcol = kb + kc;
#pragma unroll
    for (int j = 0; j < 2; ++j) {
      int seg = wave * 2 + j;
      async_copy16(A2 + (size_t)(m0 + seg * 16 + r4) * KA + acol, &As[buf][seg * 512]);
      async_copy16(B2 + (size_t)(n0 + seg * 16 + r4) * KEXP + bcol, &Bs[buf][seg * 512]);
    }
  };

  STAGE(0, 0);
  __syncthreads();

  const int rb = wr * 64 + (lane & 15);
  const int cb = wc * 64 + (lane & 15);
  const int hi8 = (lane >> 4) * 8;

  int cur = 0;
  for (int kt = 0; kt < 72; ++kt) {
    if (kt < 71) STAGE(cur ^ 1, kt + 1);
    short8 a[4], b[4];
#pragma unroll
    for (int ff = 0; ff < 4; ++ff) {
      a[ff] = *(const short8*)&As[cur][(rb + ff * 16) * 32 + hi8];
      b[ff] = *(const short8*)&Bs[cur][(cb + ff * 16) * 32 + hi8];
    }
#pragma unroll
    for (int fm = 0; fm < 4; ++fm)
#pragma unroll
      for (int fn = 0; fn < 4; ++fn)
        acc[fm][fn] = __builtin_amdgcn_mfma_f32_16x16x32_bf16(a[fm], b[fn], acc[fm][fn], 0, 0, 0);
    __syncthreads();
    cur ^= 1;
  }

  const int bimg = m0 >> 8;
#pragma unroll
  for (int fn = 0; fn < 4; ++fn) {
    int col = n0 + wc * 64 + fn * 16 + (lane & 15);
    float s = 0.0f;
#pragma unroll
    for (int fm = 0; fm < 4; ++fm) {
      int row = m0 + wr * 64 + fm * 16 + (lane >> 4) * 4;
      f32x4 v = acc[fm][fn];
      if (col < NPRO) {
        C[(size_t)(row + 0) * CKD + col] = v.x;
        C[(size_t)(row + 1) * CKD + col] = v.y;
        C[(size_t)(row + 2) * CKD + col] = v.z;
        C[(size_t)(row + 3) * CKD + col] = v.w;
      }
      s += v.x + v.y + v.z + v.w;
    }
    s += __shfl_xor(s, 16, 64);
    s += __shfl_xor(s, 32, 64);
    if (lane < 16 && col < NPRO)
      atomicAdd(&img[bimg * CKD + col], s * (1.0f / 256.0f));
  }
}

// ---------------- class logits -----------------------------------------------
__global__ __launch_bounds__(256) void cls_kernel(const float* __restrict__ img,
                                                  const float* __restrict__ sa,
                                                  const float* __restrict__ scale,
                                                  float* __restrict__ out_cls) {
  int gid = blockIdx.x * 256 + threadIdx.x;
  if (gid >= 64 * 200) return;
  int b = gid / 200, c = gid - b * 200;
  float s5[KKp];
  float mx = -1e30f;
#pragma unroll
  for (int k = 0; k < KKp; ++k) { s5[k] = sa[c * KKp + k]; mx = fmaxf(mx, s5[k]); }
  float den = 0.0f;
#pragma unroll
  for (int k = 0; k < KKp; ++k) { s5[k] = expf(s5[k] - mx); den += s5[k]; }
  float acc = 0.0f;
#pragma unroll
  for (int k = 0; k < KKp; ++k)
    acc += img[(size_t)b * CKD + c * KKp + k] * (s5[k] / den * 5.0f);
  out_cls[gid] = scale[0] * acc;
}

// ---------------- fused Sinkhorn: softmax init + 3 iters + argmax -------------
// One block per class over its sorted row range. Q is L2-resident (328 KB).
__global__ __launch_bounds__(256) void qsink_kernel(const float* __restrict__ L,
                                                    const int* __restrict__ order,
                                                    const int* __restrict__ offsets,
                                                    float* __restrict__ Q,
                                                    float* __restrict__ out_part) {
  int c = blockIdx.x;
  int s0 = offsets[c], e0 = offsets[c + 1];
  if (s0 >= e0) return;
  int t = threadIdx.x;
  int lane = t & 63, w = t >> 6;
  __shared__ float cs[KKp];
  __shared__ float wsum[4][KKp];

  // softmax init over the 5 class-c logits of each owned row
  for (int i = s0 + t; i < e0; i += 256) {
    int n = order[i];
    const float* Lr = L + (size_t)n * CKD + c * KKp;
    float q[KKp];
    float mx = -1e30f;
#pragma unroll
    for (int k = 0; k < KKp; ++k) { q[k] = Lr[k]; mx = fmaxf(mx, q[k]); }
    float den = 0.0f;
#pragma unroll
    for (int k = 0; k < KKp; ++k) { q[k] = expf(q[k] - mx); den += q[k]; }
    float inv = 1.0f / den;
#pragma unroll
    for (int k = 0; k < KKp; ++k) Q[(size_t)n * KKp + k] = q[k] * inv;
  }
  __syncthreads();

  for (int it = 0; it < 3; ++it) {
    // column sums
    float a[KKp] = {0, 0, 0, 0, 0};
    for (int i = s0 + t; i < e0; i += 256) {
      int n = order[i];
      const float* q = Q + (size_t)n * KKp;
#pragma unroll
      for (int k = 0; k < KKp; ++k) a[k] += q[k];
    }
#pragma unroll
    for (int off = 32; off; off >>= 1)
#pragma unroll
      for (int k = 0; k < KKp; ++k) a[k] += __shfl_xor(a[k], off, 64);
    if (lane == 0) {
#pragma unroll
      for (int k = 0; k < KKp; ++k) wsum[w][k] = a[k];
    }
    __syncthreads();
    if (t == 0) {
#pragma unroll
      for (int k = 0; k < KKp; ++k)
        cs[k] = wsum[0][k] + wsum[1][k] + wsum[2][k] + wsum[3][k];
    }
    __syncthreads();

    // row update (+ argmax on last iter)
    for (int i = s0 + t; i < e0; i += 256) {
      int n = order[i];
      float q[KKp];
      float r = 0.0f;
#pragma unroll
      for (int k = 0; k < KKp; ++k) {
        q[k] = Q[(size_t)n * KKp + k] / (cs[k] + 1e-12f);
        r += q[k];
      }
      float rinv = 1.0f / (r + 1e-12f);
#pragma unroll
      for (int k = 0; k < KKp; ++k) {
        q[k] *= rinv;
        Q[(size_t)n * KKp + k] = q[k];
      }
      if (it == 2) {
        float best = q[0];
        int bi = 0;
#pragma unroll
        for (int k = 1; k < KKp; ++k)
          if (q[k] > best) { best = q[k]; bi = k; }
        out_part[n] = (float)bi;
      }
    }
    __syncthreads();
  }
}

// ---------------- P_new accumulation: 32-patch chunks, flush on class change --
__global__ __launch_bounds__(256) void pnew_kernel(const int* __restrict__ order,
                                                   const int* __restrict__ pl,
                                                   const float* __restrict__ Q,
                                                   const float* __restrict__ tok,
                                                   const float* __restrict__ inv_tok,
                                                   float* __restrict__ P_acc) {
  __shared__ int idx[32], cls[32];
  int t = threadIdx.x;
  int p0 = blockIdx.x * 32;
  if (t < 32) {
    int n = order[p0 + t];
    idx[t] = n;
    cls[t] = pl[n];
  }
  __syncthreads();
  float acc[KKp][3];
#pragma unroll
  for (int k = 0; k < KKp; ++k)
#pragma unroll
    for (int s = 0; s < 3; ++s) acc[k][s] = 0.0f;
  int cur = cls[0];
  for (int i = 0; i < 32; ++i) {
    int c = cls[i];
    if (c != cur) {
#pragma unroll
      for (int k = 0; k < KKp; ++k)
#pragma unroll
        for (int s = 0; s < 3; ++s) {
          atomicAdd(&P_acc[((size_t)cur * KKp + k) * DIMD + s * 256 + t], acc[k][s]);
          acc[k][s] = 0.0f;
        }
      cur = c;
    }
    int n = idx[i];
    float it = inv_tok[n];
    float q[KKp];
#pragma unroll
    for (int k = 0; k < KKp; ++k) q[k] = Q[(size_t)n * KKp + k];
#pragma unroll
    for (int s = 0; s < 3; ++s) {
      float v = tok[(size_t)n * DIMD + s * 256 + t] * it;
#pragma unroll
      for (int k = 0; k < KKp; ++k) acc[k][s] = fmaf(q[k], v, acc[k][s]);
    }
  }
#pragma unroll
  for (int k = 0; k < KKp; ++k)
#pragma unroll
    for (int s = 0; s < 3; ++s)
      atomicAdd(&P_acc[((size_t)cur * KKp + k) * DIMD + s * 256 + t], acc[k][s]);
}

// ---------------- prototype EMA ------------------------------------------------
__global__ __launch_bounds__(256) void newproto_kernel(const float* __restrict__ proto,
                                                       const float* __restrict__ P_acc,
                                                       const int* __restrict__ offsets,
                                                       float* __restrict__ outp) {
  int gid = blockIdx.x * 256 + threadIdx.x;
  if (gid >= CC * KKp * DIMD) return;
  int c = gid / (KKp * DIMD);
  float p = proto[gid];
  bool has = offsets[c + 1] > offsets[c];
  outp[gid] = has ? (0.999f * p + 0.001f * P_acc[gid]) : p;
}

extern "C" void kernel_launch(void* const* d_in, const int* in_sizes, int n_in,
                              void* d_out, int out_size, void* d_ws, size_t ws_size,
                              hipStream_t stream) {
  const float* patch_tokens = (const float*)d_in[0];
  const float* prototypes   = (const float*)d_in[1];
  const float* sa           = (const float*)d_in[2];
  const float* scale        = (const float*)d_in[3];
  const int*   labels       = (const int*)d_in[4];
  const void*  masks        = (const void*)d_in[5];

  float* out = (float*)d_out;
  float* out_logits  = out + OUT_LOGITS;
  float* out_img     = out + OUT_IMG;
  float* out_cls     = out + OUT_CLS;
  float* out_part    = out + OUT_PART;
  float* out_newp    = out + OUT_NEWPROTO;
  float* out_pseudo  = out + OUT_PSEUDO;

  char* w = (char*)d_ws;
  float*          P_acc   = (float*)(w + WOFF_PACC);
  unsigned short* A2      = (unsigned short*)(w + WOFF_A2);
  unsigned short* B2      = (unsigned short*)(w + WOFF_B2);
  float*          inv_tok = (float*)(w + WOFF_INVTOK);
  int*            pl      = (int*)(w + WOFF_PL);
  float*          Q       = (float*)(w + WOFF_Q);
  int*            offsets = (int*)(w + WOFF_OFFSETS);
  int*            order   = (int*)(w + WOFF_ORDER);

  hipMemsetAsync(P_acc, 0, 3087360, stream);
  hipMemsetAsync(out_img, 0, (size_t)64 * CKD * sizeof(float), stream);

  prep_kernel<<<1, 1024, 0, stream>>>(masks, labels, pl, out_pseudo, offsets, order);
  conv_kernel<<<4352, 256, 0, stream>>>(patch_tokens, prototypes, A2, B2, inv_tok);

  gemm_kernel<<<dim3(128, 8), 256, 0, stream>>>(A2, B2, out_logits, out_img);

  cls_kernel<<<50, 256, 0, stream>>>(out_img, sa, scale, out_cls);
  qsink_kernel<<<CC, 256, 0, stream>>>(out_logits, order, offsets, Q, out_part);

  pnew_kernel<<<512, 256, 0, stream>>>(order, pl, Q, patch_tokens, inv_tok, P_acc);
  newproto_kernel<<<3015, 256, 0, stream>>>(prototypes, P_acc, offsets, out_newp);
}

// Round 5
// 321.066 us; speedup vs baseline: 1.1825x; 1.1825x over previous
//
#include <hip/hip_runtime.h>
#include <hip/hip_cooperative_groups.h>
#include <math.h>

namespace cg = cooperative_groups;

// Problem constants
#define NTOK 16384     // B*N_PATCH
#define NPRO 1005      // C*K
#define DIMD 768
#define CKD  1005
#define CC   201
#define KKp  5
#define BGC  200
#define KEXP 2304      // expanded K = 3*768 (hh, lh, hl)
#define KA   1536      // A2 row length ([Ah|Al])
#define NPAD 1024      // padded N

// d_out section offsets (floats)
#define OUT_LOGITS   0
#define OUT_IMG      16465920
#define OUT_CLS      (OUT_IMG + 64320)
#define OUT_PART     (OUT_CLS + 12800)
#define OUT_NEWPROTO (OUT_PART + 16384)
#define OUT_PSEUDO   (OUT_NEWPROTO + 771840)

// ws byte offsets — [0, WS_ZERO_B) is zeroed each call
#define WOFF_PACC    0ULL                  // 201*5*768*4 = 3,087,360
#define WOFF_COLSUM3 3087360ULL            // 3 iters * 1024 floats = 12,288
#define WOFF_COUNTS  3099648ULL            // 1,024
#define WOFF_FLAG    3100672ULL            // 256
#define WS_ZERO_B    3100928ULL
#define WOFF_A2      3100928ULL            // 16384*1536*2 = 50,331,648
#define WOFF_B2      53432576ULL           // 1024*2304*2  =  4,718,592
#define WOFF_INVTOK  58151168ULL           // 65,536
#define WOFF_PL      58216704ULL           // 65,536
#define WOFF_Q       58282240ULL           // 327,680
#define WOFF_OFFSETS 58609920ULL           // 1,024
#define WOFF_CURSORS 58610944ULL           // 1,024
#define WOFF_ORDER   58611968ULL           // 65,536

typedef __attribute__((ext_vector_type(8))) short short8;
typedef __attribute__((ext_vector_type(4))) float f32x4;
typedef __attribute__((ext_vector_type(4))) unsigned short usv4;

__device__ __forceinline__ unsigned short f2bf(float x) {
  unsigned int b = __float_as_uint(x);
  unsigned int r = (b + 0x7FFFu + ((b >> 16) & 1u)) >> 16;
  return (unsigned short)r;
}
__device__ __forceinline__ float bf2f(unsigned short u) {
  return __uint_as_float(((unsigned int)u) << 16);
}

__device__ __forceinline__ void async_copy16(const void* g, void* lds) {
  __builtin_amdgcn_global_load_lds(
      (const __attribute__((address_space(1))) unsigned int*)g,
      (__attribute__((address_space(3))) unsigned int*)lds, 16, 0, 0);
}

// ---------------- fused convert: tokens + prototypes -> A2 / B2 --------------
__global__ __launch_bounds__(256) void conv_kernel(const float* __restrict__ tok,
                                                   const float* __restrict__ pro,
                                                   unsigned short* __restrict__ A2,
                                                   unsigned short* __restrict__ B2,
                                                   float* __restrict__ inv_tok) {
  int wid = (blockIdx.x * 256 + threadIdx.x) >> 6;
  int lane = threadIdx.x & 63;
  if (wid >= NTOK + NPAD) return;

  if (wid < NTOK) {
    const float4* s4 = (const float4*)(tok + (size_t)wid * DIMD);
    float4 v[3];
    float s = 0.0f;
#pragma unroll
    for (int p = 0; p < 3; ++p) {
      v[p] = s4[p * 64 + lane];
      s += v[p].x * v[p].x + v[p].y * v[p].y + v[p].z * v[p].z + v[p].w * v[p].w;
    }
#pragma unroll
    for (int off = 32; off; off >>= 1) s += __shfl_xor(s, off, 64);
    float inv = 1.0f / (sqrtf(s) + 1e-12f);
    if (lane == 0) inv_tok[wid] = inv;
    unsigned short* rowp = A2 + (size_t)wid * KA;
#pragma unroll
    for (int p = 0; p < 3; ++p) {
      float x0 = v[p].x * inv, x1 = v[p].y * inv, x2 = v[p].z * inv, x3 = v[p].w * inv;
      usv4 hi, lo;
      hi.x = f2bf(x0); hi.y = f2bf(x1); hi.z = f2bf(x2); hi.w = f2bf(x3);
      lo.x = f2bf(x0 - bf2f(hi.x)); lo.y = f2bf(x1 - bf2f(hi.y));
      lo.z = f2bf(x2 - bf2f(hi.z)); lo.w = f2bf(x3 - bf2f(hi.w));
      int c = p * 256 + lane * 4;
      *(usv4*)(rowp + c) = hi;
      *(usv4*)(rowp + 768 + c) = lo;
    }
  } else {
    int pw = wid - NTOK;
    unsigned short* rowp = B2 + (size_t)pw * KEXP;
    if (pw >= NPRO) {
      usv4 z = {0, 0, 0, 0};
#pragma unroll
      for (int p = 0; p < 3; ++p) {
        int c = p * 256 + lane * 4;
        *(usv4*)(rowp + c) = z; *(usv4*)(rowp + 768 + c) = z; *(usv4*)(rowp + 1536 + c) = z;
      }
      return;
    }
    const float4* s4 = (const float4*)(pro + (size_t)pw * DIMD);
    float4 v[3];
    float s = 0.0f;
#pragma unroll
    for (int p = 0; p < 3; ++p) {
      v[p] = s4[p * 64 + lane];
      s += v[p].x * v[p].x + v[p].y * v[p].y + v[p].z * v[p].z + v[p].w * v[p].w;
    }
#pragma unroll
    for (int off = 32; off; off >>= 1) s += __shfl_xor(s, off, 64);
    float inv = 1.0f / (sqrtf(s) + 1e-12f);
#pragma unroll
    for (int p = 0; p < 3; ++p) {
      float x0 = v[p].x * inv, x1 = v[p].y * inv, x2 = v[p].z * inv, x3 = v[p].w * inv;
      usv4 hi, lo;
      hi.x = f2bf(x0); hi.y = f2bf(x1); hi.z = f2bf(x2); hi.w = f2bf(x3);
      lo.x = f2bf(x0 - bf2f(hi.x)); lo.y = f2bf(x1 - bf2f(hi.y));
      lo.z = f2bf(x2 - bf2f(hi.z)); lo.w = f2bf(x3 - bf2f(hi.w));
      int c = p * 256 + lane * 4;
      *(usv4*)(rowp + c) = hi;
      *(usv4*)(rowp + 768 + c) = hi;
      *(usv4*)(rowp + 1536 + c) = lo;
    }
  }
}

// ---------------- MFMA GEMM (byte-identical structure to round 3/4) ----------
__global__ __launch_bounds__(256, 2) void gemm_kernel(const unsigned short* __restrict__ A2,
                                                      const unsigned short* __restrict__ B2,
                                                      float* __restrict__ C,
                                                      float* __restrict__ img) {
  __shared__ unsigned short As[2][4096];   // [128 rows][32 k] bf16
  __shared__ unsigned short Bs[2][4096];
  const int tid = threadIdx.x;
  const int lane = tid & 63, wave = tid >> 6;
  const int m0 = blockIdx.x * 128, n0 = blockIdx.y * 128;
  const int wr = wave >> 1, wc = wave & 1;

  f32x4 acc[4][4];
#pragma unroll
  for (int i = 0; i < 4; ++i)
#pragma unroll
    for (int j = 0; j < 4; ++j) acc[i][j] = (f32x4){0.f, 0.f, 0.f, 0.f};

  const int r4 = lane >> 2;
  const int kc = (lane & 3) * 8;

  auto STAGE = [&](int buf, int kt) {
    int kb = kt * 32;
    int acol = (kb < KA ? kb : kb - KA) + kc;
    int bcol = kb + kc;
#pragma unroll
    for (int j = 0; j < 2; ++j) {
      int seg = wave * 2 + j;
      async_copy16(A2 + (size_t)(m0 + seg * 16 + r4) * KA + acol, &As[buf][seg * 512]);
      async_copy16(B2 + (size_t)(n0 + seg * 16 + r4) * KEXP + bcol, &Bs[buf][seg * 512]);
    }
  };

  STAGE(0, 0);
  __syncthreads();

  const int rb = wr * 64 + (lane & 15);
  const int cb = wc * 64 + (lane & 15);
  const int hi8 = (lane >> 4) * 8;

  int cur = 0;
  for (int kt = 0; kt < 72; ++kt) {
    if (kt < 71) STAGE(cur ^ 1, kt + 1);
    short8 a[4], b[4];
#pragma unroll
    for (int ff = 0; ff < 4; ++ff) {
      a[ff] = *(const short8*)&As[cur][(rb + ff * 16) * 32 + hi8];
      b[ff] = *(const short8*)&Bs[cur][(cb + ff * 16) * 32 + hi8];
    }
#pragma unroll
    for (int fm = 0; fm < 4; ++fm)
#pragma unroll
      for (int fn = 0; fn < 4; ++fn)
        acc[fm][fn] = __builtin_amdgcn_mfma_f32_16x16x32_bf16(a[fm], b[fn], acc[fm][fn], 0, 0, 0);
    __syncthreads();
    cur ^= 1;
  }

  const int bimg = m0 >> 8;
#pragma unroll
  for (int fn = 0; fn < 4; ++fn) {
    int col = n0 + wc * 64 + fn * 16 + (lane & 15);
    float s = 0.0f;
#pragma unroll
    for (int fm = 0; fm < 4; ++fm) {
      int row = m0 + wr * 64 + fm * 16 + (lane >> 4) * 4;
      f32x4 v = acc[fm][fn];
      if (col < NPRO) {
        C[(size_t)(row + 0) * CKD + col] = v.x;
        C[(size_t)(row + 1) * CKD + col] = v.y;
        C[(size_t)(row + 2) * CKD + col] = v.z;
        C[(size_t)(row + 3) * CKD + col] = v.w;
      }
      s += v.x + v.y + v.z + v.w;
    }
    s += __shfl_xor(s, 16, 64);
    s += __shfl_xor(s, 32, 64);
    if (lane < 16 && col < NPRO)
      atomicAdd(&img[bimg * CKD + col], s * (1.0f / 256.0f));
  }
}

// ---------------- class logits -----------------------------------------------
__global__ __launch_bounds__(256) void cls_kernel(const float* __restrict__ img,
                                                  const float* __restrict__ sa,
                                                  const float* __restrict__ scale,
                                                  float* __restrict__ out_cls) {
  int gid = blockIdx.x * 256 + threadIdx.x;
  if (gid >= 64 * 200) return;
  int b = gid / 200, c = gid - b * 200;
  float s5[KKp];
  float mx = -1e30f;
#pragma unroll
  for (int k = 0; k < KKp; ++k) { s5[k] = sa[c * KKp + k]; mx = fmaxf(mx, s5[k]); }
  float den = 0.0f;
#pragma unroll
  for (int k = 0; k < KKp; ++k) { s5[k] = expf(s5[k] - mx); den += s5[k]; }
  float acc = 0.0f;
#pragma unroll
  for (int k = 0; k < KKp; ++k)
    acc += img[(size_t)b * CKD + c * KKp + k] * (s5[k] / den * 5.0f);
  out_cls[gid] = scale[0] * acc;
}

// ---------------- cooperative cluster: probe+labels+sinkhorn+argmax+scatter ---
// 64 blocks (block = image), 256 threads (thread = patch). Each block touches
// exactly 2 classes: labels[b] and background. q[5] lives in registers.
__global__ __launch_bounds__(256) void cluster_kernel(const void* __restrict__ masks,
                                                      const int* __restrict__ labels,
                                                      const float* __restrict__ L,
                                                      float* __restrict__ Q,
                                                      int* __restrict__ pl,
                                                      float* __restrict__ out_pseudo,
                                                      float* __restrict__ out_part,
                                                      int* __restrict__ counts,
                                                      int* __restrict__ offsets,
                                                      int* __restrict__ cursors,
                                                      int* __restrict__ order,
                                                      float* __restrict__ colsum3,
                                                      int* __restrict__ flag) {
  cg::grid_group g = cg::this_grid();
  const int b = blockIdx.x, t = threadIdx.x;
  const int n = b * 256 + t;
  const int lane = t & 63, w = t >> 6;

  __shared__ int wcnt[4];
  __shared__ int sbase[2];
  __shared__ float red[4][2 * KKp];
  __shared__ int sc[256];

  // dtype probe: 64 blocks x 64 words = first 4096 u32 words (16 KiB)
  if (t < 64) {
    unsigned v = ((const unsigned*)masks)[b * 64 + t];
    unsigned pr = (v == 0x3F800000u) ? 1u : (v > 1u ? 2u : 0u);
    if (pr) atomicOr(flag, (int)pr);
  }
  g.sync();
  int f = __hip_atomic_load(flag, __ATOMIC_RELAXED, __HIP_MEMORY_SCOPE_AGENT);

  int m;
  if (f & 1)      m = ((const float*)masks)[n] != 0.0f;          // float32 bools
  else if (f & 2) m = ((const unsigned char*)masks)[n] != 0;     // byte-packed
  else            m = ((const int*)masks)[n] != 0;               // int32 bools
  const int cf = labels[b];                // in [0,200): never BGC
  const int lab = m ? cf : BGC;
  pl[n] = lab;
  out_pseudo[n] = (float)lab;

  // per-block fg count + stable-enough ranks (order within class is free)
  unsigned long long mk = __ballot(m != 0);
  int rkw_fg = __popcll(mk & ((1ull << lane) - 1));
  int rkw_bg = lane - rkw_fg;
  if (lane == 0) wcnt[w] = __popcll(mk);
  __syncthreads();
  int fg_before = 0;
#pragma unroll
  for (int i = 0; i < 4; ++i) fg_before += (i < w) ? wcnt[i] : 0;
  int nf = wcnt[0] + wcnt[1] + wcnt[2] + wcnt[3];
  int fgrank = fg_before + rkw_fg;
  int bgrank = (w * 64 - fg_before) + rkw_bg;
  if (t == 0) {
    atomicAdd(&counts[cf], nf);
    atomicAdd(&counts[BGC], 256 - nf);
  }

  // softmax init over own class's 5 logits (registers from here on)
  const float* Lr = L + (size_t)n * CKD + lab * KKp;
  float q[KKp];
  float mx = -1e30f;
#pragma unroll
  for (int k = 0; k < KKp; ++k) { q[k] = Lr[k]; mx = fmaxf(mx, q[k]); }
  float den = 0.0f;
#pragma unroll
  for (int k = 0; k < KKp; ++k) { q[k] = expf(q[k] - mx); den += q[k]; }
  float inv = 1.0f / den;
#pragma unroll
  for (int k = 0; k < KKp; ++k) q[k] *= inv;

  // 3 Sinkhorn iterations; per-iter zeroed colsum buffers (memset'd)
  for (int it = 0; it < 3; ++it) {
    float fgv[KKp], bgv[KKp];
#pragma unroll
    for (int k = 0; k < KKp; ++k) { fgv[k] = m ? q[k] : 0.0f; bgv[k] = m ? 0.0f : q[k]; }
#pragma unroll
    for (int off = 32; off; off >>= 1) {
#pragma unroll
      for (int k = 0; k < KKp; ++k) {
        fgv[k] += __shfl_xor(fgv[k], off, 64);
        bgv[k] += __shfl_xor(bgv[k], off, 64);
      }
    }
    if (lane == 0) {
#pragma unroll
      for (int k = 0; k < KKp; ++k) { red[w][k] = fgv[k]; red[w][KKp + k] = bgv[k]; }
    }
    __syncthreads();
    if (t < 2 * KKp) {
      float s = red[0][t] + red[1][t] + red[2][t] + red[3][t];
      int cls_ = (t < KKp) ? cf : BGC;
      int kk = (t < KKp) ? t : t - KKp;
      atomicAdd(&colsum3[it * 1024 + cls_ * KKp + kk], s);
    }
    g.sync();   // all column-sum contributions (and, for it==0, counts) visible

    if (it == 0 && b == 0) {
      // exclusive scan of counts -> offsets, cursors (single block)
      int v0 = (t < CC) ? counts[t] : 0;
      sc[t] = v0;
      __syncthreads();
      for (int off = 1; off < 256; off <<= 1) {
        int u = (t >= off) ? sc[t - off] : 0;
        __syncthreads();
        sc[t] += u;
        __syncthreads();
      }
      if (t < CC) { offsets[t] = sc[t] - v0; cursors[t] = sc[t] - v0; }
      if (t == CC - 1) offsets[CC] = sc[t];
    }

    // column normalize + row normalize (in registers)
    float r = 0.0f;
#pragma unroll
    for (int k = 0; k < KKp; ++k) {
      q[k] = q[k] / (colsum3[it * 1024 + lab * KKp + k] + 1e-12f);
      r += q[k];
    }
    float rinv = 1.0f / (r + 1e-12f);
#pragma unroll
    for (int k = 0; k < KKp; ++k) q[k] *= rinv;
    // no sync needed: next iter writes a different colsum buffer; cursors
    // (written by block 0 before the it==1 sync) are only read after it==2 sync
  }

  // final Q + argmax
  float* Qr = Q + (size_t)n * KKp;
  float best = q[0];
  int bi = 0;
#pragma unroll
  for (int k = 0; k < KKp; ++k) {
    Qr[k] = q[k];
    if (k > 0 && q[k] > best) { best = q[k]; bi = k; }
  }
  out_part[n] = (float)bi;

  // scatter into class-sorted order
  if (t == 0) {
    sbase[0] = atomicAdd(&cursors[cf], nf);
    sbase[1] = atomicAdd(&cursors[BGC], 256 - nf);
  }
  __syncthreads();
  int base = m ? sbase[0] : sbase[1];
  int rank = m ? fgrank : bgrank;
  order[base + rank] = n;
}

// ---------------- P_new accumulation: 32-patch chunks, flush on class change --
__global__ __launch_bounds__(256) void pnew_kernel(const int* __restrict__ order,
                                                   const int* __restrict__ pl,
                                                   const float* __restrict__ Q,
                                                   const float* __restrict__ tok,
                                                   const float* __restrict__ inv_tok,
                                                   float* __restrict__ P_acc) {
  __shared__ int idx[32], cls[32];
  int t = threadIdx.x;
  int p0 = blockIdx.x * 32;
  if (t < 32) {
    int n = order[p0 + t];
    idx[t] = n;
    cls[t] = pl[n];
  }
  __syncthreads();
  float acc[KKp][3];
#pragma unroll
  for (int k = 0; k < KKp; ++k)
#pragma unroll
    for (int s = 0; s < 3; ++s) acc[k][s] = 0.0f;
  int cur = cls[0];
  for (int i = 0; i < 32; ++i) {
    int c = cls[i];
    if (c != cur) {
#pragma unroll
      for (int k = 0; k < KKp; ++k)
#pragma unroll
        for (int s = 0; s < 3; ++s) {
          atomicAdd(&P_acc[((size_t)cur * KKp + k) * DIMD + s * 256 + t], acc[k][s]);
          acc[k][s] = 0.0f;
        }
      cur = c;
    }
    int n = idx[i];
    float it = inv_tok[n];
    float q[KKp];
#pragma unroll
    for (int k = 0; k < KKp; ++k) q[k] = Q[(size_t)n * KKp + k];
#pragma unroll
    for (int s = 0; s < 3; ++s) {
      float v = tok[(size_t)n * DIMD + s * 256 + t] * it;
#pragma unroll
      for (int k = 0; k < KKp; ++k) acc[k][s] = fmaf(q[k], v, acc[k][s]);
    }
  }
#pragma unroll
  for (int k = 0; k < KKp; ++k)
#pragma unroll
    for (int s = 0; s < 3; ++s)
      atomicAdd(&P_acc[((size_t)cur * KKp + k) * DIMD + s * 256 + t], acc[k][s]);
}

// ---------------- prototype EMA ------------------------------------------------
__global__ __launch_bounds__(256) void newproto_kernel(const float* __restrict__ proto,
                                                       const float* __restrict__ P_acc,
                                                       const int* __restrict__ offsets,
                                                       float* __restrict__ outp) {
  int gid = blockIdx.x * 256 + threadIdx.x;
  if (gid >= CC * KKp * DIMD) return;
  int c = gid / (KKp * DIMD);
  float p = proto[gid];
  bool has = offsets[c + 1] > offsets[c];
  outp[gid] = has ? (0.999f * p + 0.001f * P_acc[gid]) : p;
}

extern "C" void kernel_launch(void* const* d_in, const int* in_sizes, int n_in,
                              void* d_out, int out_size, void* d_ws, size_t ws_size,
                              hipStream_t stream) {
  const float* patch_tokens = (const float*)d_in[0];
  const float* prototypes   = (const float*)d_in[1];
  const float* sa           = (const float*)d_in[2];
  const float* scale        = (const float*)d_in[3];
  const int*   labels       = (const int*)d_in[4];
  const void*  masks        = (const void*)d_in[5];

  float* out = (float*)d_out;
  float* out_logits  = out + OUT_LOGITS;
  float* out_img     = out + OUT_IMG;
  float* out_cls     = out + OUT_CLS;
  float* out_part    = out + OUT_PART;
  float* out_newp    = out + OUT_NEWPROTO;
  float* out_pseudo  = out + OUT_PSEUDO;

  char* w = (char*)d_ws;
  float*          P_acc   = (float*)(w + WOFF_PACC);
  float*          colsum3 = (float*)(w + WOFF_COLSUM3);
  int*            counts  = (int*)(w + WOFF_COUNTS);
  int*            flag    = (int*)(w + WOFF_FLAG);
  unsigned short* A2      = (unsigned short*)(w + WOFF_A2);
  unsigned short* B2      = (unsigned short*)(w + WOFF_B2);
  float*          inv_tok = (float*)(w + WOFF_INVTOK);
  int*            pl      = (int*)(w + WOFF_PL);
  float*          Q       = (float*)(w + WOFF_Q);
  int*            offsets = (int*)(w + WOFF_OFFSETS);
  int*            cursors = (int*)(w + WOFF_CURSORS);
  int*            order   = (int*)(w + WOFF_ORDER);

  hipMemsetAsync(d_ws, 0, WS_ZERO_B, stream);                       // P_acc+colsum3+counts+flag
  hipMemsetAsync(out_img, 0, (size_t)64 * CKD * sizeof(float), stream);

  conv_kernel<<<4352, 256, 0, stream>>>(patch_tokens, prototypes, A2, B2, inv_tok);

  gemm_kernel<<<dim3(128, 8), 256, 0, stream>>>(A2, B2, out_logits, out_img);

  cls_kernel<<<50, 256, 0, stream>>>(out_img, sa, scale, out_cls);

  {
    const void* masks_a = masks; const int* labels_a = labels;
    const float* L_a = out_logits; float* Q_a = Q;
    int* pl_a = pl; float* pseudo_a = out_pseudo; float* part_a = out_part;
    int* counts_a = counts; int* offsets_a = offsets; int* cursors_a = cursors;
    int* order_a = order; float* colsum3_a = colsum3; int* flag_a = flag;
    void* cargs[] = {&masks_a, &labels_a, &L_a, &Q_a, &pl_a, &pseudo_a, &part_a,
                     &counts_a, &offsets_a, &cursors_a, &order_a, &colsum3_a, &flag_a};
    hipLaunchCooperativeKernel((const void*)cluster_kernel, dim3(64), dim3(256),
                               cargs, 0, stream);
  }

  pnew_kernel<<<512, 256, 0, stream>>>(order, pl, Q, patch_tokens, inv_tok, P_acc);
  newproto_kernel<<<3015, 256, 0, stream>>>(prototypes, P_acc, offsets, out_newp);
}

// Round 6
// 313.457 us; speedup vs baseline: 1.2112x; 1.0243x over previous
//
#include <hip/hip_runtime.h>
#include <hip/hip_cooperative_groups.h>
#include <math.h>

namespace cg = cooperative_groups;

// Problem constants
#define NTOK 16384     // B*N_PATCH
#define NPRO 1005      // C*K
#define DIMD 768
#define CKD  1005
#define CC   201
#define KKp  5
#define BGC  200
#define KEXP 2304      // expanded K = 3*768 (hh, lh, hl)
#define KA   1536      // A2 row length ([Ah|Al])
#define NPAD 1024      // padded N
#define NT   36        // K-tiles of 64

// d_out section offsets (floats)
#define OUT_LOGITS   0
#define OUT_IMG      16465920
#define OUT_CLS      (OUT_IMG + 64320)
#define OUT_PART     (OUT_CLS + 12800)
#define OUT_NEWPROTO (OUT_PART + 16384)
#define OUT_PSEUDO   (OUT_NEWPROTO + 771840)

// ws byte offsets — [0, WS_ZERO_B) is zeroed each call
#define WOFF_PACC    0ULL                  // 201*5*768*4 = 3,087,360
#define WOFF_COLSUM3 3087360ULL            // 3 iters * 1024 floats = 12,288
#define WOFF_COUNTS  3099648ULL            // 1,024
#define WOFF_FLAG    3100672ULL            // 256
#define WS_ZERO_B    3100928ULL
#define WOFF_A2      3100928ULL            // 16384*1536*2 = 50,331,648
#define WOFF_B2      53432576ULL           // 1024*2304*2  =  4,718,592
#define WOFF_INVTOK  58151168ULL           // 65,536
#define WOFF_PL      58216704ULL           // 65,536
#define WOFF_Q       58282240ULL           // 327,680
#define WOFF_OFFSETS 58609920ULL           // 1,024
#define WOFF_CURSORS 58610944ULL           // 1,024
#define WOFF_ORDER   58611968ULL           // 65,536

typedef __attribute__((ext_vector_type(8))) short short8;
typedef __attribute__((ext_vector_type(4))) float f32x4;
typedef __attribute__((ext_vector_type(4))) unsigned short usv4;

__device__ __forceinline__ unsigned short f2bf(float x) {
  unsigned int b = __float_as_uint(x);
  unsigned int r = (b + 0x7FFFu + ((b >> 16) & 1u)) >> 16;
  return (unsigned short)r;
}
__device__ __forceinline__ float bf2f(unsigned short u) {
  return __uint_as_float(((unsigned int)u) << 16);
}

__device__ __forceinline__ void async_copy16(const void* g, void* lds) {
  __builtin_amdgcn_global_load_lds(
      (const __attribute__((address_space(1))) unsigned int*)g,
      (__attribute__((address_space(3))) unsigned int*)lds, 16, 0, 0);
}

// ---------------- fused convert: tokens + prototypes -> A2 / B2 --------------
__global__ __launch_bounds__(256) void conv_kernel(const float* __restrict__ tok,
                                                   const float* __restrict__ pro,
                                                   unsigned short* __restrict__ A2,
                                                   unsigned short* __restrict__ B2,
                                                   float* __restrict__ inv_tok) {
  int wid = (blockIdx.x * 256 + threadIdx.x) >> 6;
  int lane = threadIdx.x & 63;
  if (wid >= NTOK + NPAD) return;

  if (wid < NTOK) {
    const float4* s4 = (const float4*)(tok + (size_t)wid * DIMD);
    float4 v[3];
    float s = 0.0f;
#pragma unroll
    for (int p = 0; p < 3; ++p) {
      v[p] = s4[p * 64 + lane];
      s += v[p].x * v[p].x + v[p].y * v[p].y + v[p].z * v[p].z + v[p].w * v[p].w;
    }
#pragma unroll
    for (int off = 32; off; off >>= 1) s += __shfl_xor(s, off, 64);
    float inv = 1.0f / (sqrtf(s) + 1e-12f);
    if (lane == 0) inv_tok[wid] = inv;
    unsigned short* rowp = A2 + (size_t)wid * KA;
#pragma unroll
    for (int p = 0; p < 3; ++p) {
      float x0 = v[p].x * inv, x1 = v[p].y * inv, x2 = v[p].z * inv, x3 = v[p].w * inv;
      usv4 hi, lo;
      hi.x = f2bf(x0); hi.y = f2bf(x1); hi.z = f2bf(x2); hi.w = f2bf(x3);
      lo.x = f2bf(x0 - bf2f(hi.x)); lo.y = f2bf(x1 - bf2f(hi.y));
      lo.z = f2bf(x2 - bf2f(hi.z)); lo.w = f2bf(x3 - bf2f(hi.w));
      int c = p * 256 + lane * 4;
      *(usv4*)(rowp + c) = hi;
      *(usv4*)(rowp + 768 + c) = lo;
    }
  } else {
    int pw = wid - NTOK;
    unsigned short* rowp = B2 + (size_t)pw * KEXP;
    if (pw >= NPRO) {
      usv4 z = {0, 0, 0, 0};
#pragma unroll
      for (int p = 0; p < 3; ++p) {
        int c = p * 256 + lane * 4;
        *(usv4*)(rowp + c) = z; *(usv4*)(rowp + 768 + c) = z; *(usv4*)(rowp + 1536 + c) = z;
      }
      return;
    }
    const float4* s4 = (const float4*)(pro + (size_t)pw * DIMD);
    float4 v[3];
    float s = 0.0f;
#pragma unroll
    for (int p = 0; p < 3; ++p) {
      v[p] = s4[p * 64 + lane];
      s += v[p].x * v[p].x + v[p].y * v[p].y + v[p].z * v[p].z + v[p].w * v[p].w;
    }
#pragma unroll
    for (int off = 32; off; off >>= 1) s += __shfl_xor(s, off, 64);
    float inv = 1.0f / (sqrtf(s) + 1e-12f);
#pragma unroll
    for (int p = 0; p < 3; ++p) {
      float x0 = v[p].x * inv, x1 = v[p].y * inv, x2 = v[p].z * inv, x3 = v[p].w * inv;
      usv4 hi, lo;
      hi.x = f2bf(x0); hi.y = f2bf(x1); hi.z = f2bf(x2); hi.w = f2bf(x3);
      lo.x = f2bf(x0 - bf2f(hi.x)); lo.y = f2bf(x1 - bf2f(hi.y));
      lo.z = f2bf(x2 - bf2f(hi.z)); lo.w = f2bf(x3 - bf2f(hi.w));
      int c = p * 256 + lane * 4;
      *(usv4*)(rowp + c) = hi;
      *(usv4*)(rowp + 768 + c) = hi;
      *(usv4*)(rowp + 1536 + c) = lo;
    }
  }
}

// ---------------- 256x256 8-phase MFMA GEMM ----------------------------------
// BM=BN=256, BK=64, 512 thr (8 waves, 2M x 4N), 128 KiB LDS:
//   A[buf][half]: buf*32768 + half*16384 ; B: +65536. half = 128 rows x 64k bf16.
// Per K-tile: 4 phases x 16 MFMA; stage 1 half-tile/phase (2 gload_lds/thread);
// vmcnt(4) once per tile (counted, never 0 in-loop). LDS XOR swizzle
// (bits 4,5 ^= bits 8,9) applied on global source + read (involution).
__global__ __launch_bounds__(512, 2) void gemm_kernel(const unsigned short* __restrict__ A2,
                                                      const unsigned short* __restrict__ B2,
                                                      float* __restrict__ C,
                                                      float* __restrict__ img) {
  extern __shared__ unsigned char lds[];
  const int tid = threadIdx.x;
  const int l = tid & 63, w = tid >> 6;
  const int wr = w >> 2, wn = w & 3;
  const int m0 = blockIdx.x * 256, n0 = blockIdx.y * 256;

  f32x4 acc[8][4];
#pragma unroll
  for (int i = 0; i < 8; ++i)
#pragma unroll
    for (int j = 0; j < 4; ++j) acc[i][j] = (f32x4){0.f, 0.f, 0.f, 0.f};

  // stage one half-tile (128 rows x 64 k) of tile t into its buffer
  auto STAGE = [&](int t, int isB, int half) {
    const int buf = t & 1;
    unsigned char* dst = lds + (isB ? 65536 : 0) + buf * 32768 + half * 16384 + w * 1024;
    const char* gsrc;
    int rs;
    if (isB) {
      gsrc = (const char*)B2 + (size_t)(n0 + half * 128) * 4608 + (size_t)t * 128;
      rs = 4608;
    } else {
      int ac = (t < 24 ? t : t - 24) * 128;   // third K-segment re-reads Ah
      gsrc = (const char*)A2 + (size_t)(m0 + half * 128) * 3072 + ac;
      rs = 3072;
    }
#pragma unroll
    for (int j = 0; j < 2; ++j) {
      int X = j * 8192 + w * 1024 + l * 16;                      // linear LDS dest pos
      int P = X ^ (((X >> 8) & 1) << 4) ^ (((X >> 9) & 1) << 5); // inverse-swz source pos
      int row = P >> 7, colb = P & 127;
      async_copy16(gsrc + (size_t)row * rs + colb, dst + j * 8192);
    }
  };

  // prologue: tile0 fully + tile1 A-halves; wait leaving 4 loads in flight
  STAGE(0, 0, 0); STAGE(0, 0, 1); STAGE(0, 1, 0); STAGE(0, 1, 1);
  STAGE(1, 0, 0); STAGE(1, 0, 1);
  asm volatile("s_waitcnt vmcnt(4)" ::: "memory");
  __builtin_amdgcn_s_barrier();

  // swizzled per-lane read offset within a fragment row
  const int lx = ((l >> 4) * 16) ^ ((l & 6) << 3);
  const int arow = (l & 15) * 128 + lx;

  short8 a0[4][2], a1[4][2], b0[2][2], b1[2][2];

#pragma unroll 1
  for (int t = 0; t < NT; ++t) {
    const int buf = t & 1;
    const unsigned char* ab = lds + buf * 32768 + wr * 16384;
    const unsigned char* bb = lds + 65536 + buf * 32768 + (wn >> 1) * 16384 + (wn & 1) * 8192;

    // ---- phase 1: read A[0-3],B[0-1]; stage B-half0(t+1); MFMA q(0,0)
#pragma unroll
    for (int fm = 0; fm < 4; ++fm)
#pragma unroll
      for (int ks = 0; ks < 2; ++ks)
        a0[fm][ks] = *(const short8*)(ab + fm * 2048 + ks * 64 + arow);
#pragma unroll
    for (int fn = 0; fn < 2; ++fn)
#pragma unroll
      for (int ks = 0; ks < 2; ++ks)
        b0[fn][ks] = *(const short8*)(bb + fn * 2048 + ks * 64 + arow);
    if (t + 1 < NT) STAGE(t + 1, 1, 0);
    __builtin_amdgcn_s_barrier();
    __builtin_amdgcn_s_setprio(1);
#pragma unroll
    for (int fm = 0; fm < 4; ++fm)
#pragma unroll
      for (int fn = 0; fn < 2; ++fn)
#pragma unroll
        for (int ks = 0; ks < 2; ++ks)
          acc[fm][fn] = __builtin_amdgcn_mfma_f32_16x16x32_bf16(a0[fm][ks], b0[fn][ks], acc[fm][fn], 0, 0, 0);
    __builtin_amdgcn_s_setprio(0);
    __builtin_amdgcn_s_barrier();

    // ---- phase 2: read A[4-7]; stage B-half1(t+1); MFMA q(1,0)
#pragma unroll
    for (int fm = 0; fm < 4; ++fm)
#pragma unroll
      for (int ks = 0; ks < 2; ++ks)
        a1[fm][ks] = *(const short8*)(ab + (4 + fm) * 2048 + ks * 64 + arow);
    if (t + 1 < NT) STAGE(t + 1, 1, 1);
    __builtin_amdgcn_s_barrier();
    __builtin_amdgcn_s_setprio(1);
#pragma unroll
    for (int fm = 0; fm < 4; ++fm)
#pragma unroll
      for (int fn = 0; fn < 2; ++fn)
#pragma unroll
        for (int ks = 0; ks < 2; ++ks)
          acc[4 + fm][fn] = __builtin_amdgcn_mfma_f32_16x16x32_bf16(a1[fm][ks], b0[fn][ks], acc[4 + fm][fn], 0, 0, 0);
    __builtin_amdgcn_s_setprio(0);
    __builtin_amdgcn_s_barrier();

    // ---- phase 3: read B[2-3]; stage A-half0(t+2); MFMA q(0,1)
#pragma unroll
    for (int fn = 0; fn < 2; ++fn)
#pragma unroll
      for (int ks = 0; ks < 2; ++ks)
        b1[fn][ks] = *(const short8*)(bb + (2 + fn) * 2048 + ks * 64 + arow);
    if (t + 2 < NT) STAGE(t + 2, 0, 0);
    __builtin_amdgcn_s_barrier();
    __builtin_amdgcn_s_setprio(1);
#pragma unroll
    for (int fm = 0; fm < 4; ++fm)
#pragma unroll
      for (int fn = 0; fn < 2; ++fn)
#pragma unroll
        for (int ks = 0; ks < 2; ++ks)
          acc[fm][2 + fn] = __builtin_amdgcn_mfma_f32_16x16x32_bf16(a0[fm][ks], b1[fn][ks], acc[fm][2 + fn], 0, 0, 0);
    __builtin_amdgcn_s_setprio(0);
    __builtin_amdgcn_s_barrier();

    // ---- phase 4: stage A-half1(t+2); MFMA q(1,1); counted vmcnt
    if (t + 2 < NT) STAGE(t + 2, 0, 1);
    __builtin_amdgcn_s_barrier();
    __builtin_amdgcn_s_setprio(1);
#pragma unroll
    for (int fm = 0; fm < 4; ++fm)
#pragma unroll
      for (int fn = 0; fn < 2; ++fn)
#pragma unroll
        for (int ks = 0; ks < 2; ++ks)
          acc[4 + fm][2 + fn] = __builtin_amdgcn_mfma_f32_16x16x32_bf16(a1[fm][ks], b1[fn][ks], acc[4 + fm][2 + fn], 0, 0, 0);
    __builtin_amdgcn_s_setprio(0);
    if (t < NT - 2) asm volatile("s_waitcnt vmcnt(4)" ::: "memory");
    else if (t == NT - 2) asm volatile("s_waitcnt vmcnt(0)" ::: "memory");
    __builtin_amdgcn_s_barrier();
  }

  // epilogue: C writes + fused mean-pool (block rows = exactly one image)
  const int bimg = m0 >> 8;
#pragma unroll
  for (int fn = 0; fn < 4; ++fn) {
    int col = n0 + wn * 64 + fn * 16 + (l & 15);
    float s = 0.0f;
#pragma unroll
    for (int fm = 0; fm < 8; ++fm) {
      int row = m0 + wr * 128 + fm * 16 + (l >> 4) * 4;
      f32x4 v = acc[fm][fn];
      if (col < NPRO) {
        C[(size_t)(row + 0) * CKD + col] = v.x;
        C[(size_t)(row + 1) * CKD + col] = v.y;
        C[(size_t)(row + 2) * CKD + col] = v.z;
        C[(size_t)(row + 3) * CKD + col] = v.w;
      }
      s += v.x + v.y + v.z + v.w;
    }
    s += __shfl_xor(s, 16, 64);
    s += __shfl_xor(s, 32, 64);
    if (l < 16 && col < NPRO)
      atomicAdd(&img[bimg * CKD + col], s * (1.0f / 256.0f));
  }
}

// ---------------- cooperative cluster: cls + probe + labels + sinkhorn + ... --
__global__ __launch_bounds__(256) void cluster_kernel(const void* __restrict__ masks,
                                                      const int* __restrict__ labels,
                                                      const float* __restrict__ L,
                                                      const float* __restrict__ img,
                                                      const float* __restrict__ sa,
                                                      const float* __restrict__ scale,
                                                      float* __restrict__ out_cls,
                                                      float* __restrict__ Q,
                                                      int* __restrict__ pl,
                                                      float* __restrict__ out_pseudo,
                                                      float* __restrict__ out_part,
                                                      int* __restrict__ counts,
                                                      int* __restrict__ offsets,
                                                      int* __restrict__ cursors,
                                                      int* __restrict__ order,
                                                      float* __restrict__ colsum3,
                                                      int* __restrict__ flag) {
  cg::grid_group g = cg::this_grid();
  const int b = blockIdx.x, t = threadIdx.x;
  const int n = b * 256 + t;
  const int lane = t & 63, w = t >> 6;

  __shared__ int wcnt[4];
  __shared__ int sbase[2];
  __shared__ float red[4][2 * KKp];
  __shared__ int sc[256];

  // fused class-head: out_cls[b][t] for t<200
  if (t < 200) {
    float s5[KKp];
    float mx = -1e30f;
#pragma unroll
    for (int k = 0; k < KKp; ++k) { s5[k] = sa[t * KKp + k]; mx = fmaxf(mx, s5[k]); }
    float den = 0.0f;
#pragma unroll
    for (int k = 0; k < KKp; ++k) { s5[k] = expf(s5[k] - mx); den += s5[k]; }
    float a = 0.0f;
#pragma unroll
    for (int k = 0; k < KKp; ++k)
      a += img[(size_t)b * CKD + t * KKp + k] * (s5[k] / den * 5.0f);
    out_cls[b * 200 + t] = scale[0] * a;
  }

  // dtype probe: 64 blocks x 64 words = first 4096 u32 words (16 KiB)
  if (t < 64) {
    unsigned v = ((const unsigned*)masks)[b * 64 + t];
    unsigned pr = (v == 0x3F800000u) ? 1u : (v > 1u ? 2u : 0u);
    if (pr) atomicOr(flag, (int)pr);
  }
  g.sync();
  int f = __hip_atomic_load(flag, __ATOMIC_RELAXED, __HIP_MEMORY_SCOPE_AGENT);

  int m;
  if (f & 1)      m = ((const float*)masks)[n] != 0.0f;
  else if (f & 2) m = ((const unsigned char*)masks)[n] != 0;
  else            m = ((const int*)masks)[n] != 0;
  const int cf = labels[b];
  const int lab = m ? cf : BGC;
  pl[n] = lab;
  out_pseudo[n] = (float)lab;

  unsigned long long mk = __ballot(m != 0);
  int rkw_fg = __popcll(mk & ((1ull << lane) - 1));
  int rkw_bg = lane - rkw_fg;
  if (lane == 0) wcnt[w] = __popcll(mk);
  __syncthreads();
  int fg_before = 0;
#pragma unroll
  for (int i = 0; i < 4; ++i) fg_before += (i < w) ? wcnt[i] : 0;
  int nf = wcnt[0] + wcnt[1] + wcnt[2] + wcnt[3];
  int fgrank = fg_before + rkw_fg;
  int bgrank = (w * 64 - fg_before) + rkw_bg;
  if (t == 0) {
    atomicAdd(&counts[cf], nf);
    atomicAdd(&counts[BGC], 256 - nf);
  }

  const float* Lr = L + (size_t)n * CKD + lab * KKp;
  float q[KKp];
  float mx = -1e30f;
#pragma unroll
  for (int k = 0; k < KKp; ++k) { q[k] = Lr[k]; mx = fmaxf(mx, q[k]); }
  float den = 0.0f;
#pragma unroll
  for (int k = 0; k < KKp; ++k) { q[k] = expf(q[k] - mx); den += q[k]; }
  float inv = 1.0f / den;
#pragma unroll
  for (int k = 0; k < KKp; ++k) q[k] *= inv;

  for (int it = 0; it < 3; ++it) {
    float fgv[KKp], bgv[KKp];
#pragma unroll
    for (int k = 0; k < KKp; ++k) { fgv[k] = m ? q[k] : 0.0f; bgv[k] = m ? 0.0f : q[k]; }
#pragma unroll
    for (int off = 32; off; off >>= 1) {
#pragma unroll
      for (int k = 0; k < KKp; ++k) {
        fgv[k] += __shfl_xor(fgv[k], off, 64);
        bgv[k] += __shfl_xor(bgv[k], off, 64);
      }
    }
    if (lane == 0) {
#pragma unroll
      for (int k = 0; k < KKp; ++k) { red[w][k] = fgv[k]; red[w][KKp + k] = bgv[k]; }
    }
    __syncthreads();
    if (t < 2 * KKp) {
      float s = red[0][t] + red[1][t] + red[2][t] + red[3][t];
      int cls_ = (t < KKp) ? cf : BGC;
      int kk = (t < KKp) ? t : t - KKp;
      atomicAdd(&colsum3[it * 1024 + cls_ * KKp + kk], s);
    }
    g.sync();

    if (it == 0 && b == 0) {
      int v0 = (t < CC) ? counts[t] : 0;
      sc[t] = v0;
      __syncthreads();
      for (int off = 1; off < 256; off <<= 1) {
        int u = (t >= off) ? sc[t - off] : 0;
        __syncthreads();
        sc[t] += u;
        __syncthreads();
      }
      if (t < CC) { offsets[t] = sc[t] - v0; cursors[t] = sc[t] - v0; }
      if (t == CC - 1) offsets[CC] = sc[t];
    }

    float r = 0.0f;
#pragma unroll
    for (int k = 0; k < KKp; ++k) {
      q[k] = q[k] / (colsum3[it * 1024 + lab * KKp + k] + 1e-12f);
      r += q[k];
    }
    float rinv = 1.0f / (r + 1e-12f);
#pragma unroll
    for (int k = 0; k < KKp; ++k) q[k] *= rinv;
  }

  float* Qr = Q + (size_t)n * KKp;
  float best = q[0];
  int bi = 0;
#pragma unroll
  for (int k = 0; k < KKp; ++k) {
    Qr[k] = q[k];
    if (k > 0 && q[k] > best) { best = q[k]; bi = k; }
  }
  out_part[n] = (float)bi;

  if (t == 0) {
    sbase[0] = atomicAdd(&cursors[cf], nf);
    sbase[1] = atomicAdd(&cursors[BGC], 256 - nf);
  }
  __syncthreads();
  int base = m ? sbase[0] : sbase[1];
  int rank = m ? fgrank : bgrank;
  order[base + rank] = n;
}

// ---------------- P_new accumulation: 32-patch chunks, flush on class change --
__global__ __launch_bounds__(256) void pnew_kernel(const int* __restrict__ order,
                                                   const int* __restrict__ pl,
                                                   const float* __restrict__ Q,
                                                   const float* __restrict__ tok,
                                                   const float* __restrict__ inv_tok,
                                                   float* __restrict__ P_acc) {
  __shared__ int idx[32], cls[32];
  int t = threadIdx.x;
  int p0 = blockIdx.x * 32;
  if (t < 32) {
    int n = order[p0 + t];
    idx[t] = n;
    cls[t] = pl[n];
  }
  __syncthreads();
  float acc[KKp][3];
#pragma unroll
  for (int k = 0; k < KKp; ++k)
#pragma unroll
    for (int s = 0; s < 3; ++s) acc[k][s] = 0.0f;
  int cur = cls[0];
  for (int i = 0; i < 32; ++i) {
    int c = cls[i];
    if (c != cur) {
#pragma unroll
      for (int k = 0; k < KKp; ++k)
#pragma unroll
        for (int s = 0; s < 3; ++s) {
          atomicAdd(&P_acc[((size_t)cur * KKp + k) * DIMD + s * 256 + t], acc[k][s]);
          acc[k][s] = 0.0f;
        }
      cur = c;
    }
    int n = idx[i];
    float it = inv_tok[n];
    float q[KKp];
#pragma unroll
    for (int k = 0; k < KKp; ++k) q[k] = Q[(size_t)n * KKp + k];
#pragma unroll
    for (int s = 0; s < 3; ++s) {
      float v = tok[(size_t)n * DIMD + s * 256 + t] * it;
#pragma unroll
      for (int k = 0; k < KKp; ++k) acc[k][s] = fmaf(q[k], v, acc[k][s]);
    }
  }
#pragma unroll
  for (int k = 0; k < KKp; ++k)
#pragma unroll
    for (int s = 0; s < 3; ++s)
      atomicAdd(&P_acc[((size_t)cur * KKp + k) * DIMD + s * 256 + t], acc[k][s]);
}

// ---------------- prototype EMA ------------------------------------------------
__global__ __launch_bounds__(256) void newproto_kernel(const float* __restrict__ proto,
                                                       const float* __restrict__ P_acc,
                                                       const int* __restrict__ offsets,
                                                       float* __restrict__ outp) {
  int gid = blockIdx.x * 256 + threadIdx.x;
  if (gid >= CC * KKp * DIMD) return;
  int c = gid / (KKp * DIMD);
  float p = proto[gid];
  bool has = offsets[c + 1] > offsets[c];
  outp[gid] = has ? (0.999f * p + 0.001f * P_acc[gid]) : p;
}

extern "C" void kernel_launch(void* const* d_in, const int* in_sizes, int n_in,
                              void* d_out, int out_size, void* d_ws, size_t ws_size,
                              hipStream_t stream) {
  const float* patch_tokens = (const float*)d_in[0];
  const float* prototypes   = (const float*)d_in[1];
  const float* sa           = (const float*)d_in[2];
  const float* scale        = (const float*)d_in[3];
  const int*   labels       = (const int*)d_in[4];
  const void*  masks        = (const void*)d_in[5];

  float* out = (float*)d_out;
  float* out_logits  = out + OUT_LOGITS;
  float* out_img     = out + OUT_IMG;
  float* out_cls     = out + OUT_CLS;
  float* out_part    = out + OUT_PART;
  float* out_newp    = out + OUT_NEWPROTO;
  float* out_pseudo  = out + OUT_PSEUDO;

  char* w = (char*)d_ws;
  float*          P_acc   = (float*)(w + WOFF_PACC);
  float*          colsum3 = (float*)(w + WOFF_COLSUM3);
  int*            counts  = (int*)(w + WOFF_COUNTS);
  int*            flag    = (int*)(w + WOFF_FLAG);
  unsigned short* A2      = (unsigned short*)(w + WOFF_A2);
  unsigned short* B2      = (unsigned short*)(w + WOFF_B2);
  float*          inv_tok = (float*)(w + WOFF_INVTOK);
  int*            pl      = (int*)(w + WOFF_PL);
  float*          Q       = (float*)(w + WOFF_Q);
  int*            offsets = (int*)(w + WOFF_OFFSETS);
  int*            cursors = (int*)(w + WOFF_CURSORS);
  int*            order   = (int*)(w + WOFF_ORDER);

  // allow 128 KiB dynamic LDS for the 256^2 GEMM (idempotent, cheap)
  hipFuncSetAttribute((const void*)gemm_kernel,
                      hipFuncAttributeMaxDynamicSharedMemorySize, 131072);

  hipMemsetAsync(d_ws, 0, WS_ZERO_B, stream);
  hipMemsetAsync(out_img, 0, (size_t)64 * CKD * sizeof(float), stream);

  conv_kernel<<<4352, 256, 0, stream>>>(patch_tokens, prototypes, A2, B2, inv_tok);

  gemm_kernel<<<dim3(64, 4), 512, 131072, stream>>>(A2, B2, out_logits, out_img);

  {
    const void* masks_a = masks; const int* labels_a = labels;
    const float* L_a = out_logits; const float* img_a = out_img;
    const float* sa_a = sa; const float* scale_a = scale; float* cls_a = out_cls;
    float* Q_a = Q;
    int* pl_a = pl; float* pseudo_a = out_pseudo; float* part_a = out_part;
    int* counts_a = counts; int* offsets_a = offsets; int* cursors_a = cursors;
    int* order_a = order; float* colsum3_a = colsum3; int* flag_a = flag;
    void* cargs[] = {&masks_a, &labels_a, &L_a, &img_a, &sa_a, &scale_a, &cls_a,
                     &Q_a, &pl_a, &pseudo_a, &part_a,
                     &counts_a, &offsets_a, &cursors_a, &order_a, &colsum3_a, &flag_a};
    hipLaunchCooperativeKernel((const void*)cluster_kernel, dim3(64), dim3(256),
                               cargs, 0, stream);
  }

  pnew_kernel<<<512, 256, 0, stream>>>(order, pl, Q, patch_tokens, inv_tok, P_acc);
  newproto_kernel<<<3015, 256, 0, stream>>>(prototypes, P_acc, offsets, out_newp);
}

// Round 8
// 308.799 us; speedup vs baseline: 1.2295x; 1.0151x over previous
//
#include <hip/hip_runtime.h>
#include <hip/hip_cooperative_groups.h>
#include <math.h>

namespace cg = cooperative_groups;

// Problem constants
#define NTOK 16384     // B*N_PATCH
#define NPRO 1005      // C*K
#define DIMD 768
#define CKD  1005
#define CC   201
#define KKp  5
#define BGC  200
#define KEXP 2304      // expanded K = 3*768 (hh, lh, hl)
#define KA   1536      // A2 row length ([Ah|Al])
#define NPAD 1024      // padded N
#define NT   36        // K-tiles of 64

// d_out section offsets (floats)
#define OUT_LOGITS   0
#define OUT_IMG      16465920
#define OUT_CLS      (OUT_IMG + 64320)
#define OUT_PART     (OUT_CLS + 12800)
#define OUT_NEWPROTO (OUT_PART + 16384)
#define OUT_PSEUDO   (OUT_NEWPROTO + 771840)

// ws byte offsets — [0, WS_ZERO_B) is zeroed each call
#define WOFF_PACC    0ULL                  // 201*5*768*4 = 3,087,360
#define WOFF_COLSUM3 3087360ULL            // 3 iters * 1024 floats = 12,288
#define WOFF_COUNTS  3099648ULL            // 1,024
#define WOFF_FLAG    3100672ULL            // 256
#define WS_ZERO_B    3100928ULL
#define WOFF_A2      3100928ULL            // 16384*1536*2 = 50,331,648
#define WOFF_B2      53432576ULL           // 1024*2304*2  =  4,718,592
#define WOFF_INVTOK  58151168ULL           // 65,536
#define WOFF_PL      58216704ULL           // 65,536
#define WOFF_Q       58282240ULL           // 327,680
#define WOFF_OFFSETS 58609920ULL           // 1,024
#define WOFF_CURSORS 58610944ULL           // 1,024
#define WOFF_ORDER   58611968ULL           // 65,536

typedef __attribute__((ext_vector_type(8))) short short8;
typedef __attribute__((ext_vector_type(4))) float f32x4;
typedef __attribute__((ext_vector_type(4))) unsigned short usv4;

__device__ __forceinline__ unsigned short f2bf(float x) {
  unsigned int b = __float_as_uint(x);
  unsigned int r = (b + 0x7FFFu + ((b >> 16) & 1u)) >> 16;
  return (unsigned short)r;
}
__device__ __forceinline__ float bf2f(unsigned short u) {
  return __uint_as_float(((unsigned int)u) << 16);
}

__device__ __forceinline__ void async_copy16(const void* g, void* lds) {
  __builtin_amdgcn_global_load_lds(
      (const __attribute__((address_space(1))) unsigned int*)g,
      (__attribute__((address_space(3))) unsigned int*)lds, 16, 0, 0);
}

// ---------------- fused convert: tokens + prototypes -> A2 / B2 --------------
__global__ __launch_bounds__(256) void conv_kernel(const float* __restrict__ tok,
                                                   const float* __restrict__ pro,
                                                   unsigned short* __restrict__ A2,
                                                   unsigned short* __restrict__ B2,
                                                   float* __restrict__ inv_tok) {
  int wid = (blockIdx.x * 256 + threadIdx.x) >> 6;
  int lane = threadIdx.x & 63;
  if (wid >= NTOK + NPAD) return;

  if (wid < NTOK) {
    const float4* s4 = (const float4*)(tok + (size_t)wid * DIMD);
    float4 v[3];
    float s = 0.0f;
#pragma unroll
    for (int p = 0; p < 3; ++p) {
      v[p] = s4[p * 64 + lane];
      s += v[p].x * v[p].x + v[p].y * v[p].y + v[p].z * v[p].z + v[p].w * v[p].w;
    }
#pragma unroll
    for (int off = 32; off; off >>= 1) s += __shfl_xor(s, off, 64);
    float inv = 1.0f / (sqrtf(s) + 1e-12f);
    if (lane == 0) inv_tok[wid] = inv;
    unsigned short* rowp = A2 + (size_t)wid * KA;
#pragma unroll
    for (int p = 0; p < 3; ++p) {
      float x0 = v[p].x * inv, x1 = v[p].y * inv, x2 = v[p].z * inv, x3 = v[p].w * inv;
      usv4 hi, lo;
      hi.x = f2bf(x0); hi.y = f2bf(x1); hi.z = f2bf(x2); hi.w = f2bf(x3);
      lo.x = f2bf(x0 - bf2f(hi.x)); lo.y = f2bf(x1 - bf2f(hi.y));
      lo.z = f2bf(x2 - bf2f(hi.z)); lo.w = f2bf(x3 - bf2f(hi.w));
      int c = p * 256 + lane * 4;
      *(usv4*)(rowp + c) = hi;
      *(usv4*)(rowp + 768 + c) = lo;
    }
  } else {
    int pw = wid - NTOK;
    unsigned short* rowp = B2 + (size_t)pw * KEXP;
    if (pw >= NPRO) {
      usv4 z = {0, 0, 0, 0};
#pragma unroll
      for (int p = 0; p < 3; ++p) {
        int c = p * 256 + lane * 4;
        *(usv4*)(rowp + c) = z; *(usv4*)(rowp + 768 + c) = z; *(usv4*)(rowp + 1536 + c) = z;
      }
      return;
    }
    const float4* s4 = (const float4*)(pro + (size_t)pw * DIMD);
    float4 v[3];
    float s = 0.0f;
#pragma unroll
    for (int p = 0; p < 3; ++p) {
      v[p] = s4[p * 64 + lane];
      s += v[p].x * v[p].x + v[p].y * v[p].y + v[p].z * v[p].z + v[p].w * v[p].w;
    }
#pragma unroll
    for (int off = 32; off; off >>= 1) s += __shfl_xor(s, off, 64);
    float inv = 1.0f / (sqrtf(s) + 1e-12f);
#pragma unroll
    for (int p = 0; p < 3; ++p) {
      float x0 = v[p].x * inv, x1 = v[p].y * inv, x2 = v[p].z * inv, x3 = v[p].w * inv;
      usv4 hi, lo;
      hi.x = f2bf(x0); hi.y = f2bf(x1); hi.z = f2bf(x2); hi.w = f2bf(x3);
      lo.x = f2bf(x0 - bf2f(hi.x)); lo.y = f2bf(x1 - bf2f(hi.y));
      lo.z = f2bf(x2 - bf2f(hi.z)); lo.w = f2bf(x3 - bf2f(hi.w));
      int c = p * 256 + lane * 4;
      *(usv4*)(rowp + c) = hi;
      *(usv4*)(rowp + 768 + c) = hi;
      *(usv4*)(rowp + 1536 + c) = lo;
    }
  }
}

// ---------------- 256x256 8-phase MFMA GEMM ----------------------------------
// BM=BN=256, BK=64, 512 thr (8 waves, 2M x 4N), 128 KiB LDS.
// LDS XOR swizzle (3-bit, conflict-free): byte bits [6:4] ^= bits [9:7]
// (chunk ^= row&7) — involution at 16B granularity; applied as
// inverse-permuted GLOBAL source in STAGE + swizzled read offsets.
__global__ __launch_bounds__(512, 2) void gemm_kernel(const unsigned short* __restrict__ A2,
                                                      const unsigned short* __restrict__ B2,
                                                      float* __restrict__ C,
                                                      float* __restrict__ img) {
  extern __shared__ unsigned char lds[];
  const int tid = threadIdx.x;
  const int l = tid & 63, w = tid >> 6;
  const int wr = w >> 2, wn = w & 3;
  const int m0 = blockIdx.x * 256, n0 = blockIdx.y * 256;

  f32x4 acc[8][4];
#pragma unroll
  for (int i = 0; i < 8; ++i)
#pragma unroll
    for (int j = 0; j < 4; ++j) acc[i][j] = (f32x4){0.f, 0.f, 0.f, 0.f};

  // stage one half-tile (128 rows x 64 k) of tile t into its buffer
  auto STAGE = [&](int t, int isB, int half) {
    const int buf = t & 1;
    unsigned char* dst = lds + (isB ? 65536 : 0) + buf * 32768 + half * 16384 + w * 1024;
    const char* gsrc;
    int rs;
    if (isB) {
      gsrc = (const char*)B2 + (size_t)(n0 + half * 128) * 4608 + (size_t)t * 128;
      rs = 4608;
    } else {
      int ac = (t < 24 ? t : t - 24) * 128;   // third K-segment re-reads Ah
      gsrc = (const char*)A2 + (size_t)(m0 + half * 128) * 3072 + ac;
      rs = 3072;
    }
#pragma unroll
    for (int j = 0; j < 2; ++j) {
      int X = j * 8192 + w * 1024 + l * 16;              // linear LDS dest pos
      int P = X ^ (((X >> 7) & 7) << 4);                 // inverse-swz source pos
      int row = P >> 7, colb = P & 127;
      async_copy16(gsrc + (size_t)row * rs + colb, dst + j * 8192);
    }
  };

  // prologue: tile0 fully + tile1 A-halves; wait leaving 4 loads in flight
  STAGE(0, 0, 0); STAGE(0, 0, 1); STAGE(0, 1, 0); STAGE(0, 1, 1);
  STAGE(1, 0, 0); STAGE(1, 0, 1);
  asm volatile("s_waitcnt vmcnt(4)" ::: "memory");
  __builtin_amdgcn_s_barrier();

  // conflict-free swizzled fragment-read offsets (row r15, chunk ^ (r&7))
  const int r15 = l & 15;
  const int cb = l >> 4;           // 0..3
  const int rx7 = l & 7;
  const int off0 = r15 * 128 + (((cb) ^ rx7) << 4);        // ks=0: chunk=cb
  const int off1 = r15 * 128 + (((4 + cb) ^ rx7) << 4);    // ks=1: chunk=4+cb

  short8 a0[4][2], a1[4][2], b0[2][2], b1[2][2];

#pragma unroll 1
  for (int t = 0; t < NT; ++t) {
    const int buf = t & 1;
    const unsigned char* ab = lds + buf * 32768 + wr * 16384;
    const unsigned char* bb = lds + 65536 + buf * 32768 + (wn >> 1) * 16384 + (wn & 1) * 8192;

    // ---- phase 1: read A[0-3],B[0-1]; stage B-half0(t+1); MFMA q(0,0)
#pragma unroll
    for (int fm = 0; fm < 4; ++fm) {
      a0[fm][0] = *(const short8*)(ab + fm * 2048 + off0);
      a0[fm][1] = *(const short8*)(ab + fm * 2048 + off1);
    }
#pragma unroll
    for (int fn = 0; fn < 2; ++fn) {
      b0[fn][0] = *(const short8*)(bb + fn * 2048 + off0);
      b0[fn][1] = *(const short8*)(bb + fn * 2048 + off1);
    }
    if (t + 1 < NT) STAGE(t + 1, 1, 0);
    __builtin_amdgcn_s_barrier();
    __builtin_amdgcn_s_setprio(1);
#pragma unroll
    for (int fm = 0; fm < 4; ++fm)
#pragma unroll
      for (int fn = 0; fn < 2; ++fn)
#pragma unroll
        for (int ks = 0; ks < 2; ++ks)
          acc[fm][fn] = __builtin_amdgcn_mfma_f32_16x16x32_bf16(a0[fm][ks], b0[fn][ks], acc[fm][fn], 0, 0, 0);
    __builtin_amdgcn_s_setprio(0);
    __builtin_amdgcn_s_barrier();

    // ---- phase 2: read A[4-7]; stage B-half1(t+1); MFMA q(1,0)
#pragma unroll
    for (int fm = 0; fm < 4; ++fm) {
      a1[fm][0] = *(const short8*)(ab + (4 + fm) * 2048 + off0);
      a1[fm][1] = *(const short8*)(ab + (4 + fm) * 2048 + off1);
    }
    if (t + 1 < NT) STAGE(t + 1, 1, 1);
    __builtin_amdgcn_s_barrier();
    __builtin_amdgcn_s_setprio(1);
#pragma unroll
    for (int fm = 0; fm < 4; ++fm)
#pragma unroll
      for (int fn = 0; fn < 2; ++fn)
#pragma unroll
        for (int ks = 0; ks < 2; ++ks)
          acc[4 + fm][fn] = __builtin_amdgcn_mfma_f32_16x16x32_bf16(a1[fm][ks], b0[fn][ks], acc[4 + fm][fn], 0, 0, 0);
    __builtin_amdgcn_s_setprio(0);
    __builtin_amdgcn_s_barrier();

    // ---- phase 3: read B[2-3]; stage A-half0(t+2); MFMA q(0,1)
#pragma unroll
    for (int fn = 0; fn < 2; ++fn) {
      b1[fn][0] = *(const short8*)(bb + (2 + fn) * 2048 + off0);
      b1[fn][1] = *(const short8*)(bb + (2 + fn) * 2048 + off1);
    }
    if (t + 2 < NT) STAGE(t + 2, 0, 0);
    __builtin_amdgcn_s_barrier();
    __builtin_amdgcn_s_setprio(1);
#pragma unroll
    for (int fm = 0; fm < 4; ++fm)
#pragma unroll
      for (int fn = 0; fn < 2; ++fn)
#pragma unroll
        for (int ks = 0; ks < 2; ++ks)
          acc[fm][2 + fn] = __builtin_amdgcn_mfma_f32_16x16x32_bf16(a0[fm][ks], b1[fn][ks], acc[fm][2 + fn], 0, 0, 0);
    __builtin_amdgcn_s_setprio(0);
    __builtin_amdgcn_s_barrier();

    // ---- phase 4: stage A-half1(t+2); MFMA q(1,1); counted vmcnt
    if (t + 2 < NT) STAGE(t + 2, 0, 1);
    __builtin_amdgcn_s_barrier();
    __builtin_amdgcn_s_setprio(1);
#pragma unroll
    for (int fm = 0; fm < 4; ++fm)
#pragma unroll
      for (int fn = 0; fn < 2; ++fn)
#pragma unroll
        for (int ks = 0; ks < 2; ++ks)
          acc[4 + fm][2 + fn] = __builtin_amdgcn_mfma_f32_16x16x32_bf16(a1[fm][ks], b1[fn][ks], acc[4 + fm][2 + fn], 0, 0, 0);
    __builtin_amdgcn_s_setprio(0);
    if (t < NT - 2) asm volatile("s_waitcnt vmcnt(4)" ::: "memory");
    else if (t == NT - 2) asm volatile("s_waitcnt vmcnt(0)" ::: "memory");
    __builtin_amdgcn_s_barrier();
  }

  // epilogue: C writes + fused mean-pool (block rows = exactly one image)
  const int bimg = m0 >> 8;
#pragma unroll
  for (int fn = 0; fn < 4; ++fn) {
    int col = n0 + wn * 64 + fn * 16 + (l & 15);
    float s = 0.0f;
#pragma unroll
    for (int fm = 0; fm < 8; ++fm) {
      int row = m0 + wr * 128 + fm * 16 + (l >> 4) * 4;
      f32x4 v = acc[fm][fn];
      if (col < NPRO) {
        C[(size_t)(row + 0) * CKD + col] = v.x;
        C[(size_t)(row + 1) * CKD + col] = v.y;
        C[(size_t)(row + 2) * CKD + col] = v.z;
        C[(size_t)(row + 3) * CKD + col] = v.w;
      }
      s += v.x + v.y + v.z + v.w;
    }
    s += __shfl_xor(s, 16, 64);
    s += __shfl_xor(s, 32, 64);
    if (l < 16 && col < NPRO)
      atomicAdd(&img[bimg * CKD + col], s * (1.0f / 256.0f));
  }
}

// ---------------- cooperative cluster: cls + probe + labels + sinkhorn + ... --
__global__ __launch_bounds__(256) void cluster_kernel(const void* __restrict__ masks,
                                                      const int* __restrict__ labels,
                                                      const float* __restrict__ L,
                                                      const float* __restrict__ img,
                                                      const float* __restrict__ sa,
                                                      const float* __restrict__ scale,
                                                      float* __restrict__ out_cls,
                                                      float* __restrict__ Q,
                                                      int* __restrict__ pl,
                                                      float* __restrict__ out_pseudo,
                                                      float* __restrict__ out_part,
                                                      int* __restrict__ counts,
                                                      int* __restrict__ offsets,
                                                      int* __restrict__ cursors,
                                                      int* __restrict__ order,
                                                      float* __restrict__ colsum3,
                                                      int* __restrict__ flag) {
  cg::grid_group g = cg::this_grid();
  const int b = blockIdx.x, t = threadIdx.x;
  const int n = b * 256 + t;
  const int lane = t & 63, w = t >> 6;

  __shared__ int wcnt[4];
  __shared__ int sbase[2];
  __shared__ float red[4][2 * KKp];
  __shared__ int sc[256];

  // fused class-head: out_cls[b][t] for t<200
  if (t < 200) {
    float s5[KKp];
    float mx = -1e30f;
#pragma unroll
    for (int k = 0; k < KKp; ++k) { s5[k] = sa[t * KKp + k]; mx = fmaxf(mx, s5[k]); }
    float den = 0.0f;
#pragma unroll
    for (int k = 0; k < KKp; ++k) { s5[k] = expf(s5[k] - mx); den += s5[k]; }
    float a = 0.0f;
#pragma unroll
    for (int k = 0; k < KKp; ++k)
      a += img[(size_t)b * CKD + t * KKp + k] * (s5[k] / den * 5.0f);
    out_cls[b * 200 + t] = scale[0] * a;
  }

  // dtype probe: 64 blocks x 64 words = first 4096 u32 words (16 KiB)
  if (t < 64) {
    unsigned v = ((const unsigned*)masks)[b * 64 + t];
    unsigned pr = (v == 0x3F800000u) ? 1u : (v > 1u ? 2u : 0u);
    if (pr) atomicOr(flag, (int)pr);
  }
  g.sync();
  int f = __hip_atomic_load(flag, __ATOMIC_RELAXED, __HIP_MEMORY_SCOPE_AGENT);

  int m;
  if (f & 1)      m = ((const float*)masks)[n] != 0.0f;
  else if (f & 2) m = ((const unsigned char*)masks)[n] != 0;
  else            m = ((const int*)masks)[n] != 0;
  const int cf = labels[b];
  const int lab = m ? cf : BGC;
  pl[n] = lab;
  out_pseudo[n] = (float)lab;

  unsigned long long mk = __ballot(m != 0);
  int rkw_fg = __popcll(mk & ((1ull << lane) - 1));
  int rkw_bg = lane - rkw_fg;
  if (lane == 0) wcnt[w] = __popcll(mk);
  __syncthreads();
  int fg_before = 0;
#pragma unroll
  for (int i = 0; i < 4; ++i) fg_before += (i < w) ? wcnt[i] : 0;
  int nf = wcnt[0] + wcnt[1] + wcnt[2] + wcnt[3];
  int fgrank = fg_before + rkw_fg;
  int bgrank = (w * 64 - fg_before) + rkw_bg;
  if (t == 0) {
    atomicAdd(&counts[cf], nf);
    atomicAdd(&counts[BGC], 256 - nf);
  }

  const float* Lr = L + (size_t)n * CKD + lab * KKp;
  float q[KKp];
  float mx = -1e30f;
#pragma unroll
  for (int k = 0; k < KKp; ++k) { q[k] = Lr[k]; mx = fmaxf(mx, q[k]); }
  float den = 0.0f;
#pragma unroll
  for (int k = 0; k < KKp; ++k) { q[k] = expf(q[k] - mx); den += q[k]; }
  float inv = 1.0f / den;
#pragma unroll
  for (int k = 0; k < KKp; ++k) q[k] *= inv;

  for (int it = 0; it < 3; ++it) {
    float fgv[KKp], bgv[KKp];
#pragma unroll
    for (int k = 0; k < KKp; ++k) { fgv[k] = m ? q[k] : 0.0f; bgv[k] = m ? 0.0f : q[k]; }
#pragma unroll
    for (int off = 32; off; off >>= 1) {
#pragma unroll
      for (int k = 0; k < KKp; ++k) {
        fgv[k] += __shfl_xor(fgv[k], off, 64);
        bgv[k] += __shfl_xor(bgv[k], off, 64);
      }
    }
    if (lane == 0) {
#pragma unroll
      for (int k = 0; k < KKp; ++k) { red[w][k] = fgv[k]; red[w][KKp + k] = bgv[k]; }
    }
    __syncthreads();
    if (t < 2 * KKp) {
      float s = red[0][t] + red[1][t] + red[2][t] + red[3][t];
      int cls_ = (t < KKp) ? cf : BGC;
      int kk = (t < KKp) ? t : t - KKp;
      atomicAdd(&colsum3[it * 1024 + cls_ * KKp + kk], s);
    }
    g.sync();

    if (it == 0 && b == 0) {
      int v0 = (t < CC) ? counts[t] : 0;
      sc[t] = v0;
      __syncthreads();
      for (int off = 1; off < 256; off <<= 1) {
        int u = (t >= off) ? sc[t - off] : 0;
        __syncthreads();
        sc[t] += u;
        __syncthreads();
      }
      if (t < CC) { offsets[t] = sc[t] - v0; cursors[t] = sc[t] - v0; }
      if (t == CC - 1) offsets[CC] = sc[t];
    }

    float r = 0.0f;
#pragma unroll
    for (int k = 0; k < KKp; ++k) {
      q[k] = q[k] / (colsum3[it * 1024 + lab * KKp + k] + 1e-12f);
      r += q[k];
    }
    float rinv = 1.0f / (r + 1e-12f);
#pragma unroll
    for (int k = 0; k < KKp; ++k) q[k] *= rinv;
  }

  float* Qr = Q + (size_t)n * KKp;
  float best = q[0];
  int bi = 0;
#pragma unroll
  for (int k = 0; k < KKp; ++k) {
    Qr[k] = q[k];
    if (k > 0 && q[k] > best) { best = q[k]; bi = k; }
  }
  out_part[n] = (float)bi;

  if (t == 0) {
    sbase[0] = atomicAdd(&cursors[cf], nf);
    sbase[1] = atomicAdd(&cursors[BGC], 256 - nf);
  }
  __syncthreads();
  int base = m ? sbase[0] : sbase[1];
  int rank = m ? fgrank : bgrank;
  order[base + rank] = n;
}

// ---------------- P_new accumulation: 32-patch chunks, flush on class change --
__global__ __launch_bounds__(256) void pnew_kernel(const int* __restrict__ order,
                                                   const int* __restrict__ pl,
                                                   const float* __restrict__ Q,
                                                   const float* __restrict__ tok,
                                                   const float* __restrict__ inv_tok,
                                                   float* __restrict__ P_acc) {
  __shared__ int idx[32], cls[32];
  int t = threadIdx.x;
  int p0 = blockIdx.x * 32;
  if (t < 32) {
    int n = order[p0 + t];
    idx[t] = n;
    cls[t] = pl[n];
  }
  __syncthreads();
  float acc[KKp][3];
#pragma unroll
  for (int k = 0; k < KKp; ++k)
#pragma unroll
    for (int s = 0; s < 3; ++s) acc[k][s] = 0.0f;
  int cur = cls[0];
  for (int i = 0; i < 32; ++i) {
    int c = cls[i];
    if (c != cur) {
#pragma unroll
      for (int k = 0; k < KKp; ++k)
#pragma unroll
        for (int s = 0; s < 3; ++s) {
          atomicAdd(&P_acc[((size_t)cur * KKp + k) * DIMD + s * 256 + t], acc[k][s]);
          acc[k][s] = 0.0f;
        }
      cur = c;
    }
    int n = idx[i];
    float it = inv_tok[n];
    float q[KKp];
#pragma unroll
    for (int k = 0; k < KKp; ++k) q[k] = Q[(size_t)n * KKp + k];
#pragma unroll
    for (int s = 0; s < 3; ++s) {
      float v = tok[(size_t)n * DIMD + s * 256 + t] * it;
#pragma unroll
      for (int k = 0; k < KKp; ++k) acc[k][s] = fmaf(q[k], v, acc[k][s]);
    }
  }
#pragma unroll
  for (int k = 0; k < KKp; ++k)
#pragma unroll
    for (int s = 0; s < 3; ++s)
      atomicAdd(&P_acc[((size_t)cur * KKp + k) * DIMD + s * 256 + t], acc[k][s]);
}

// ---------------- prototype EMA ------------------------------------------------
__global__ __launch_bounds__(256) void newproto_kernel(const float* __restrict__ proto,
                                                       const float* __restrict__ P_acc,
                                                       const int* __restrict__ offsets,
                                                       float* __restrict__ outp) {
  int gid = blockIdx.x * 256 + threadIdx.x;
  if (gid >= CC * KKp * DIMD) return;
  int c = gid / (KKp * DIMD);
  float p = proto[gid];
  bool has = offsets[c + 1] > offsets[c];
  outp[gid] = has ? (0.999f * p + 0.001f * P_acc[gid]) : p;
}

extern "C" void kernel_launch(void* const* d_in, const int* in_sizes, int n_in,
                              void* d_out, int out_size, void* d_ws, size_t ws_size,
                              hipStream_t stream) {
  const float* patch_tokens = (const float*)d_in[0];
  const float* prototypes   = (const float*)d_in[1];
  const float* sa           = (const float*)d_in[2];
  const float* scale        = (const float*)d_in[3];
  const int*   labels       = (const int*)d_in[4];
  const void*  masks        = (const void*)d_in[5];

  float* out = (float*)d_out;
  float* out_logits  = out + OUT_LOGITS;
  float* out_img     = out + OUT_IMG;
  float* out_cls     = out + OUT_CLS;
  float* out_part    = out + OUT_PART;
  float* out_newp    = out + OUT_NEWPROTO;
  float* out_pseudo  = out + OUT_PSEUDO;

  char* w = (char*)d_ws;
  float*          P_acc   = (float*)(w + WOFF_PACC);
  float*          colsum3 = (float*)(w + WOFF_COLSUM3);
  int*            counts  = (int*)(w + WOFF_COUNTS);
  int*            flag    = (int*)(w + WOFF_FLAG);
  unsigned short* A2      = (unsigned short*)(w + WOFF_A2);
  unsigned short* B2      = (unsigned short*)(w + WOFF_B2);
  float*          inv_tok = (float*)(w + WOFF_INVTOK);
  int*            pl      = (int*)(w + WOFF_PL);
  float*          Q       = (float*)(w + WOFF_Q);
  int*            offsets = (int*)(w + WOFF_OFFSETS);
  int*            cursors = (int*)(w + WOFF_CURSORS);
  int*            order   = (int*)(w + WOFF_ORDER);

  // allow 128 KiB dynamic LDS for the 256^2 GEMM (idempotent, cheap)
  hipFuncSetAttribute((const void*)gemm_kernel,
                      hipFuncAttributeMaxDynamicSharedMemorySize, 131072);

  hipMemsetAsync(d_ws, 0, WS_ZERO_B, stream);
  hipMemsetAsync(out_img, 0, (size_t)64 * CKD * sizeof(float), stream);

  conv_kernel<<<4352, 256, 0, stream>>>(patch_tokens, prototypes, A2, B2, inv_tok);

  gemm_kernel<<<dim3(64, 4), 512, 131072, stream>>>(A2, B2, out_logits, out_img);

  {
    const void* masks_a = masks; const int* labels_a = labels;
    const float* L_a = out_logits; const float* img_a = out_img;
    const float* sa_a = sa; const float* scale_a = scale; float* cls_a = out_cls;
    float* Q_a = Q;
    int* pl_a = pl; float* pseudo_a = out_pseudo; float* part_a = out_part;
    int* counts_a = counts; int* offsets_a = offsets; int* cursors_a = cursors;
    int* order_a = order; float* colsum3_a = colsum3; int* flag_a = flag;
    void* cargs[] = {&masks_a, &labels_a, &L_a, &img_a, &sa_a, &scale_a, &cls_a,
                     &Q_a, &pl_a, &pseudo_a, &part_a,
                     &counts_a, &offsets_a, &cursors_a, &order_a, &colsum3_a, &flag_a};
    hipLaunchCooperativeKernel((const void*)cluster_kernel, dim3(64), dim3(256),
                               cargs, 0, stream);
  }

  pnew_kernel<<<512, 256, 0, stream>>>(order, pl, Q, patch_tokens, inv_tok, P_acc);
  newproto_kernel<<<3015, 256, 0, stream>>>(prototypes, P_acc, offsets, out_newp);
}